// Round 1
// baseline (19270.174 us; speedup 1.0000x reference)
//
#include <hip/hip_runtime.h>

// GRU scan, T=512 B=64 D=1024. Persistent cooperative kernel:
// 256 WGs (4 M-groups x 64 col-groups), 256 thr (4 waves, K split 256/wave).
// Weights as persistent register MFMA B-fragments. Grid barrier per step.

typedef __attribute__((ext_vector_type(8))) short short8;
typedef __attribute__((ext_vector_type(4))) float f32x4;

#define DEV static __device__ __forceinline__

constexpr int TT = 512, BB = 64, DD = 1024, TD = 3072;

// workspace layout
constexpr size_t WS_BAR = 256;        // unsigned[513] barrier area (ctr g at +g*32 words, root at word 512)
constexpr size_t WS_H = 8192;         // h buffers: hi0, lo0, hi1, lo1 (each 64*1024*2B = 128KB)
constexpr size_t H_BYTES = (size_t)BB * DD * 2;
constexpr size_t WS_NEED = WS_H + 4 * H_BYTES;

DEV unsigned short f2bf(float f) {   // RNE float->bf16
    unsigned u = __builtin_bit_cast(unsigned, f);
    u += 0x7FFFu + ((u >> 16) & 1u);
    return (unsigned short)(u >> 16);
}
DEV float bf2f(unsigned short s) { return __builtin_bit_cast(float, ((unsigned)s) << 16); }

// ---------------- prepass: zero h-buf0 + barrier, detect resets element stride ----------------
__global__ void prep_kernel(const unsigned char* __restrict__ resets, unsigned char* __restrict__ ws) {
    const int bid = blockIdx.x, tid = threadIdx.x;
    if (bid < 256) {
        // zero h buffers buf0 hi+lo: 256KB
        *(unsigned*)(ws + WS_H + (size_t)(bid * 256 + tid) * 4) = 0u;
    } else {
        unsigned* w32 = (unsigned*)ws;
        for (int i = tid; i < 2048; i += 256) w32[i] = 0u;  // zero flags + barrier (8KB)
        __shared__ int ca, cb, cc;
        if (tid == 0) { ca = 0; cb = 0; cc = 0; }
        __syncthreads();
        int la = 0, lb = 0, lc = 0;
        for (int o = tid * 16; o < tid * 16 + 16; ++o) {
            unsigned char v = resets[o];           // safe: any plausible dtype buffer >= 32KB
            if (v) {
                if ((o & 3) == 0) la = 1; else lb = 1;
                if ((o & 7) == 4) lc = 1;
            }
        }
        if (la) atomicOr(&ca, 1);
        if (lb) atomicOr(&cb, 1);
        if (lc) atomicOr(&cc, 1);
        __syncthreads();
        if (tid == 0) {
            unsigned stride, boff = 0;
            if (ca && cb)       { stride = 1; }            // uint8/int8 bool
            else if (!ca && cb) { stride = 4; boff = 3; }  // float32 0.0/1.0 (exp byte)
            else if (ca && cc)  { stride = 4; }            // int32
            else if (ca)        { stride = 8; }            // int64
            else                { stride = 4; }            // all-false: any works
            w32[0] = stride; w32[1] = boff;
        }
    }
}

// ---------------- main persistent kernel ----------------
__launch_bounds__(256, 1)
__global__ void gru_kernel(const float* __restrict__ x, const float* __restrict__ Wi,
                           const float* __restrict__ bi, const float* __restrict__ Wh,
                           const float* __restrict__ bhn, const unsigned char* __restrict__ resets,
                           float* __restrict__ out, unsigned char* __restrict__ ws) {
    const int tid = threadIdx.x;
    const int wg = blockIdx.x;
    const int lane = tid & 63;
    const int kw = tid >> 6;          // wave id: K-slice [kw*256, kw*256+256)
    const int mgrp = wg >> 6;         // M-group: rows [mgrp*16, +16)
    const int c0 = (wg & 63) * 16;    // h-column group

    unsigned* bar = (unsigned*)(ws + WS_BAR);
    const unsigned rstride = ((const unsigned*)ws)[0];
    const unsigned rboff   = ((const unsigned*)ws)[1];

    unsigned short* hb_hi0 = (unsigned short*)(ws + WS_H);
    unsigned short* hb_lo0 = (unsigned short*)(ws + WS_H + H_BYTES);
    unsigned short* hb_hi1 = (unsigned short*)(ws + WS_H + 2 * H_BYTES);
    unsigned short* hb_lo1 = (unsigned short*)(ws + WS_H + 3 * H_BYTES);

    const int lrow = lane & 15;          // MFMA A row / B col within tile
    const int lk = (lane >> 4) * 8;      // k sub-block

    // ---- one-time: gather persistent B fragments (Wi_hi, Wh_hi, Wh_lo) : 288 VGPR ----
    short8 bih[3][8], bhh[3][8], bhl[3][8];
#pragma unroll
    for (int nt = 0; nt < 3; ++nt) {
        const int col = nt * DD + c0 + lrow;
#pragma unroll
        for (int kt = 0; kt < 8; ++kt) {
            const int kb = (kw * 8 + kt) * 32 + lk;
            short8 a, c, d;
#pragma unroll
            for (int j = 0; j < 8; ++j) {
                float wi = Wi[(size_t)(kb + j) * TD + col];
                a[j] = (short)f2bf(wi);
                float wh = Wh[(size_t)(kb + j) * TD + col];
                unsigned short h2 = f2bf(wh);
                c[j] = (short)h2;
                d[j] = (short)f2bf(wh - bf2f(h2));
            }
            bih[nt][kt] = a; bhh[nt][kt] = c; bhl[nt][kt] = d;
        }
    }

    // ---- per-thread epilogue constants ----
    const int eb = tid >> 4, ej = tid & 15;
    const int brow_e = mgrp * 16 + eb;
    const int ce = c0 + ej;
    const float bi_r = bi[ce], bi_z = bi[DD + ce], bi_n = bi[2 * DD + ce];
    const float bh_n = bhn[ce];
    float h_local = 0.f;   // premasked f32 copy of owned h element

    const int aoff = (mgrp * 16 + lrow) * DD + kw * 256 + lk;  // A-fragment element offset

    __shared__ float part[4][6][16][16];   // [kw][slot][row=b][col] K-partials

    int cur = 0;
    for (int t = 0; t < TT; ++t) {
        f32x4 acc[6] = {f32x4{0}, f32x4{0}, f32x4{0}, f32x4{0}, f32x4{0}, f32x4{0}};
        const float* xp = x + (size_t)t * (BB * DD) + aoff;
        const unsigned short* hhp = (cur == 0 ? hb_hi0 : hb_hi1) + aoff;
        const unsigned short* hlp = (cur == 0 ? hb_lo0 : hb_lo1) + aoff;

#pragma unroll
        for (int kt = 0; kt < 8; ++kt) {
            f32x4 xa = *(const f32x4*)(xp + kt * 32);
            f32x4 xb = *(const f32x4*)(xp + kt * 32 + 4);
            short8 hh = *(const short8*)(hhp + kt * 32);
            short8 hl = *(const short8*)(hlp + kt * 32);
            short8 xh, xl;
#pragma unroll
            for (int j = 0; j < 4; ++j) {
                unsigned short p = f2bf(xa[j]);
                xh[j] = (short)p; xl[j] = (short)f2bf(xa[j] - bf2f(p));
                unsigned short q = f2bf(xb[j]);
                xh[4 + j] = (short)q; xl[4 + j] = (short)f2bf(xb[j] - bf2f(q));
            }
            // gi: (x_hi + x_lo) @ Wi_hi ; gh: h_hi@Wh_hi + h_lo@Wh_hi + h_hi@Wh_lo
#pragma unroll
            for (int nt = 0; nt < 3; ++nt)
                acc[nt] = __builtin_amdgcn_mfma_f32_16x16x32_bf16(xh, bih[nt][kt], acc[nt], 0, 0, 0);
#pragma unroll
            for (int nt = 0; nt < 3; ++nt)
                acc[3 + nt] = __builtin_amdgcn_mfma_f32_16x16x32_bf16(hh, bhh[nt][kt], acc[3 + nt], 0, 0, 0);
#pragma unroll
            for (int nt = 0; nt < 3; ++nt)
                acc[nt] = __builtin_amdgcn_mfma_f32_16x16x32_bf16(xl, bih[nt][kt], acc[nt], 0, 0, 0);
#pragma unroll
            for (int nt = 0; nt < 3; ++nt)
                acc[3 + nt] = __builtin_amdgcn_mfma_f32_16x16x32_bf16(hl, bhh[nt][kt], acc[3 + nt], 0, 0, 0);
#pragma unroll
            for (int nt = 0; nt < 3; ++nt)
                acc[3 + nt] = __builtin_amdgcn_mfma_f32_16x16x32_bf16(hh, bhl[nt][kt], acc[3 + nt], 0, 0, 0);
        }

        // ---- K-reduction across waves via LDS ----
        const int prow = (lane >> 4) * 4;
#pragma unroll
        for (int s = 0; s < 6; ++s)
#pragma unroll
            for (int i = 0; i < 4; ++i)
                part[kw][s][prow + i][lrow] = acc[s][i];
        __syncthreads();

        float g[6];
#pragma unroll
        for (int s = 0; s < 6; ++s)
            g[s] = part[0][s][eb][ej] + part[1][s][eb][ej] + part[2][s][eb][ej] + part[3][s][eb][ej];

        // ---- gates (flax GRUCell) ----
        float r = 1.f / (1.f + __expf(-(g[0] + bi_r + g[3])));
        float z = 1.f / (1.f + __expf(-(g[1] + bi_z + g[4])));
        float pre = g[2] + bi_n + r * (g[5] + bh_n);
        float e2 = __expf(2.f * pre);
        float n = 1.f - 2.f / (e2 + 1.f);
        float hnew = (1.f - z) * n + z * h_local;

        out[(size_t)t * (BB * DD) + brow_e * DD + ce] = hnew;

        if (t < TT - 1) {
            // premask with resets[t+1] and publish hi/lo bf16 state
            unsigned char rs = resets[(size_t)((t + 1) * BB + brow_e) * rstride + rboff];
            float heff = rs ? 0.f : hnew;
            h_local = heff;
            unsigned short ph = f2bf(heff);
            unsigned short* whi = (cur == 0 ? hb_hi1 : hb_hi0);
            unsigned short* wlo = (cur == 0 ? hb_lo1 : hb_lo0);
            whi[brow_e * DD + ce] = ph;
            wlo[brow_e * DD + ce] = f2bf(heff - bf2f(ph));

            // ---- grid barrier (each wave drains its own stores first) ----
            __threadfence();
            __syncthreads();
            if (tid == 0) {
                const unsigned grp = (unsigned)(wg >> 4);
                unsigned old = __hip_atomic_fetch_add(&bar[grp * 32], 1u,
                                                      __ATOMIC_RELAXED, __HIP_MEMORY_SCOPE_AGENT);
                if ((old & 15u) == 15u)
                    __hip_atomic_fetch_add(&bar[512], 1u, __ATOMIC_RELAXED, __HIP_MEMORY_SCOPE_AGENT);
                const unsigned target = (unsigned)(t + 1) * 16u;
                while (__hip_atomic_load(&bar[512], __ATOMIC_RELAXED, __HIP_MEMORY_SCOPE_AGENT) < target)
                    __builtin_amdgcn_s_sleep(1);
                __threadfence();
            }
            __syncthreads();
            cur ^= 1;
        }
    }
}

extern "C" void kernel_launch(void* const* d_in, const int* in_sizes, int n_in,
                              void* d_out, int out_size, void* d_ws, size_t ws_size,
                              hipStream_t stream) {
    const float* x = (const float*)d_in[0];
    const float* Wi = (const float*)d_in[1];
    const float* bi = (const float*)d_in[2];
    const float* Wh = (const float*)d_in[3];
    const float* bhn = (const float*)d_in[4];
    const unsigned char* resets = (const unsigned char*)d_in[5];
    float* out = (float*)d_out;
    unsigned char* ws = (unsigned char*)d_ws;

    if (ws_size < WS_NEED) return;  // would corrupt memory otherwise

    hipLaunchKernelGGL(prep_kernel, dim3(257), dim3(256), 0, stream, resets, ws);

    void* args[] = {(void*)&x, (void*)&Wi, (void*)&bi, (void*)&Wh,
                    (void*)&bhn, (void*)&resets, (void*)&out, (void*)&ws};
    hipError_t err = hipLaunchCooperativeKernel((const void*)gru_kernel, dim3(256), dim3(256),
                                                args, 0, stream);
    if (err != hipSuccess) {
        // fallback: plain launch — 256 WGs of 256 thr (1 per CU) co-reside on an idle MI355X
        hipLaunchKernelGGL(gru_kernel, dim3(256), dim3(256), 0, stream,
                           x, Wi, bi, Wh, bhn, resets, out, ws);
    }
}

// Round 2
// 5466.754 us; speedup vs baseline: 3.5250x; 3.5250x over previous
//
#include <hip/hip_runtime.h>

// GRU scan, T=512 B=64 D=1024. Persistent cooperative kernel:
// 256 WGs (4 M-groups x 64 col-groups), 512 thr (8 waves, K split 128/wave).
// Weights as persistent register MFMA B-fragments.
// Cross-step h exchange via device-coherent (sc1) loads/stores — NO threadfence.

typedef __attribute__((ext_vector_type(8))) short short8;
typedef __attribute__((ext_vector_type(4))) float f32x4;
typedef __attribute__((ext_vector_type(4))) unsigned int u32x4;

#define DEV static __device__ __forceinline__

constexpr int TT = 512, BB = 64, DD = 1024, TD = 3072;

// workspace layout
constexpr size_t WS_BAR = 256;                  // barrier ctrs (group g at word g*32, root at word 512)
constexpr size_t WS_H = 8192;                   // two packed h buffers (u32 per element: hi<<16|lo)
constexpr size_t H_WORDS = (size_t)BB * DD;     // 65536 words = 256 KB each
constexpr size_t WS_NEED = WS_H + 2 * H_WORDS * 4;

DEV unsigned short f2bf(float f) {   // RNE float->bf16
    unsigned u = __builtin_bit_cast(unsigned, f);
    u += 0x7FFFu + ((u >> 16) & 1u);
    return (unsigned short)(u >> 16);
}
DEV float bf2f(unsigned short s) { return __builtin_bit_cast(float, ((unsigned)s) << 16); }

DEV u32x4 coh_load4(const unsigned* p) {        // device-coherent 16B load (bypasses L2)
    u32x4 r;
    asm volatile("global_load_dwordx4 %0, %1, off sc1" : "=v"(r) : "v"(p));
    return r;  // NOT ready until vm_drain()!
}
DEV void coh_store(unsigned* p, unsigned v) {   // device-coherent 4B store
    asm volatile("global_store_dword %0, %1, off sc1" :: "v"(p), "v"(v) : "memory");
}
DEV void vm_drain() {
    asm volatile("s_waitcnt vmcnt(0)" ::: "memory");
    __builtin_amdgcn_sched_barrier(0);          // rule #18: block MFMA hoist past waitcnt
}

// ---------------- prepass: zero h-buf0 + barrier, detect resets element stride ----------------
__global__ void prep_kernel(const unsigned char* __restrict__ resets, unsigned char* __restrict__ ws) {
    const int bid = blockIdx.x, tid = threadIdx.x;
    if (bid < 256) {
        // zero packed h buffer 0 (256 KB): 256 WGs x 256 thr x 1 word
        ((unsigned*)(ws + WS_H))[bid * 256 + tid] = 0u;
    } else {
        unsigned* w32 = (unsigned*)ws;
        for (int i = tid; i < 2048; i += 256) w32[i] = 0u;  // zero stride info + barrier area
        __shared__ int ca, cb, cc;
        if (tid == 0) { ca = 0; cb = 0; cc = 0; }
        __syncthreads();
        int la = 0, lb = 0, lc = 0;
        for (int o = tid * 16; o < tid * 16 + 16; ++o) {
            unsigned char v = resets[o];           // safe: any plausible dtype buffer >= 32KB
            if (v) {
                if ((o & 3) == 0) la = 1; else lb = 1;
                if ((o & 7) == 4) lc = 1;
            }
        }
        if (la) atomicOr(&ca, 1);
        if (lb) atomicOr(&cb, 1);
        if (lc) atomicOr(&cc, 1);
        __syncthreads();
        if (tid == 0) {
            unsigned stride, boff = 0;
            if (ca && cb)       { stride = 1; }            // uint8/int8 bool
            else if (!ca && cb) { stride = 4; boff = 3; }  // float32 0.0/1.0 (exp byte)
            else if (ca && cc)  { stride = 4; }            // int32
            else if (ca)        { stride = 8; }            // int64
            else                { stride = 4; }            // all-false: any works
            w32[0] = stride; w32[1] = boff;
        }
    }
}

// ---------------- main persistent kernel ----------------
__launch_bounds__(512, 2)
__global__ void gru_kernel(const float* __restrict__ x, const float* __restrict__ Wi,
                           const float* __restrict__ bi, const float* __restrict__ Wh,
                           const float* __restrict__ bhn, const unsigned char* __restrict__ resets,
                           float* __restrict__ out, unsigned char* __restrict__ ws) {
    const int tid = threadIdx.x;
    const int wg = blockIdx.x;
    const int lane = tid & 63;
    const int kw = tid >> 6;          // wave id 0..7: K-slice [kw*128, +128)
    const int mgrp = wg >> 6;         // M-group: rows [mgrp*16, +16)
    const int c0 = (wg & 63) * 16;    // h-column group

    unsigned* bar = (unsigned*)(ws + WS_BAR);
    const unsigned rstride = ((const unsigned*)ws)[0];
    const unsigned rboff   = ((const unsigned*)ws)[1];

    unsigned* hb0 = (unsigned*)(ws + WS_H);
    unsigned* hb1 = hb0 + H_WORDS;

    const int lrow = lane & 15;          // MFMA A row / B col within tile
    const int lk = (lane >> 4) * 8;      // k sub-block

    // ---- one-time: gather persistent B fragments (Wi_hi, Wh_hi, Wh_lo): 144 VGPR ----
    short8 bih[3][4], bhh[3][4], bhl[3][4];
#pragma unroll
    for (int nt = 0; nt < 3; ++nt) {
        const int col = nt * DD + c0 + lrow;
#pragma unroll
        for (int kt = 0; kt < 4; ++kt) {
            const int kb = kw * 128 + kt * 32 + lk;
            short8 a, c, d;
#pragma unroll
            for (int j = 0; j < 8; ++j) {
                float wi = Wi[(size_t)(kb + j) * TD + col];
                a[j] = (short)f2bf(wi);
                float wh = Wh[(size_t)(kb + j) * TD + col];
                unsigned short h2 = f2bf(wh);
                c[j] = (short)h2;
                d[j] = (short)f2bf(wh - bf2f(h2));
            }
            bih[nt][kt] = a; bhh[nt][kt] = c; bhl[nt][kt] = d;
        }
    }

    // ---- per-thread epilogue constants (meaningful for tid<256) ----
    const int eb = (tid & 255) >> 4, ej = tid & 15;
    const int brow_e = mgrp * 16 + eb;
    const int ce = c0 + ej;
    const float bi_r = bi[ce], bi_z = bi[DD + ce], bi_n = bi[2 * DD + ce];
    const float bh_n = bhn[ce];
    float h_local = 0.f;   // premasked f32 copy of owned h element

    const int arow = mgrp * 16 + lrow;
    const size_t axoff = (size_t)arow * DD + kw * 128 + lk;  // x A-fragment element offset
    const unsigned hoff = (unsigned)(arow * DD + kw * 128 + lk);

    __shared__ float part[8][6][16][17];   // [kw][slot][row=b][col] K-partials (pad 17)

    int cur = 0;
    for (int t = 0; t < TT; ++t) {
        // ---- issue coherent h loads for all 4 k-tiles (ready after vm_drain) ----
        const unsigned* hbr = (cur ? hb1 : hb0) + hoff;
        u32x4 hp[8];
#pragma unroll
        for (int kt = 0; kt < 4; ++kt) {
            hp[2 * kt]     = coh_load4(hbr + kt * 32);
            hp[2 * kt + 1] = coh_load4(hbr + kt * 32 + 4);
        }

        // ---- x loads + bf16 split conversion (overlaps h-load latency) ----
        const float* xp = x + (size_t)t * (BB * DD) + axoff;
        short8 xh[4], xl[4];
#pragma unroll
        for (int kt = 0; kt < 4; ++kt) {
            f32x4 xa = *(const f32x4*)(xp + kt * 32);
            f32x4 xb = *(const f32x4*)(xp + kt * 32 + 4);
#pragma unroll
            for (int j = 0; j < 4; ++j) {
                unsigned short p = f2bf(xa[j]);
                xh[kt][j] = (short)p; xl[kt][j] = (short)f2bf(xa[j] - bf2f(p));
                unsigned short q = f2bf(xb[j]);
                xh[kt][4 + j] = (short)q; xl[kt][4 + j] = (short)f2bf(xb[j] - bf2f(q));
            }
        }

        vm_drain();   // hp[] now valid

        f32x4 acc[6] = {f32x4{0}, f32x4{0}, f32x4{0}, f32x4{0}, f32x4{0}, f32x4{0}};
#pragma unroll
        for (int kt = 0; kt < 4; ++kt) {
            short8 hh, hl;
#pragma unroll
            for (int j = 0; j < 4; ++j) {
                unsigned w0 = hp[2 * kt][j], w1 = hp[2 * kt + 1][j];
                hh[j] = (short)(w0 >> 16);     hl[j] = (short)(w0 & 0xffffu);
                hh[4 + j] = (short)(w1 >> 16); hl[4 + j] = (short)(w1 & 0xffffu);
            }
            // gi: (x_hi + x_lo) @ Wi_hi ; gh: h_hi@Wh_hi + h_lo@Wh_hi + h_hi@Wh_lo
#pragma unroll
            for (int nt = 0; nt < 3; ++nt)
                acc[nt] = __builtin_amdgcn_mfma_f32_16x16x32_bf16(xh[kt], bih[nt][kt], acc[nt], 0, 0, 0);
#pragma unroll
            for (int nt = 0; nt < 3; ++nt)
                acc[3 + nt] = __builtin_amdgcn_mfma_f32_16x16x32_bf16(hh, bhh[nt][kt], acc[3 + nt], 0, 0, 0);
#pragma unroll
            for (int nt = 0; nt < 3; ++nt)
                acc[nt] = __builtin_amdgcn_mfma_f32_16x16x32_bf16(xl[kt], bih[nt][kt], acc[nt], 0, 0, 0);
#pragma unroll
            for (int nt = 0; nt < 3; ++nt)
                acc[3 + nt] = __builtin_amdgcn_mfma_f32_16x16x32_bf16(hl, bhh[nt][kt], acc[3 + nt], 0, 0, 0);
#pragma unroll
            for (int nt = 0; nt < 3; ++nt)
                acc[3 + nt] = __builtin_amdgcn_mfma_f32_16x16x32_bf16(hh, bhl[nt][kt], acc[3 + nt], 0, 0, 0);
        }

        // ---- K-reduction across 8 waves via LDS ----
        const int prow = (lane >> 4) * 4;
#pragma unroll
        for (int s = 0; s < 6; ++s)
#pragma unroll
            for (int i = 0; i < 4; ++i)
                part[kw][s][prow + i][lrow] = acc[s][i];
        __syncthreads();

        if (tid < 256) {
            float g[6];
#pragma unroll
            for (int s = 0; s < 6; ++s) {
                float sum = 0.f;
#pragma unroll
                for (int k = 0; k < 8; ++k) sum += part[k][s][eb][ej];
                g[s] = sum;
            }

            // ---- gates (flax GRUCell) ----
            float r = 1.f / (1.f + __expf(-(g[0] + bi_r + g[3])));
            float z = 1.f / (1.f + __expf(-(g[1] + bi_z + g[4])));
            float pre = g[2] + bi_n + r * (g[5] + bh_n);
            float e2 = __expf(2.f * pre);
            float n = 1.f - 2.f / (e2 + 1.f);
            float hnew = (1.f - z) * n + z * h_local;

            out[(size_t)t * (BB * DD) + brow_e * DD + ce] = hnew;

            if (t < TT - 1) {
                // premask with resets[t+1], publish packed bf16 hi|lo state (coherent)
                unsigned char rs = resets[(size_t)((t + 1) * BB + brow_e) * rstride + rboff];
                float heff = rs ? 0.f : hnew;
                h_local = heff;
                unsigned short ph = f2bf(heff);
                unsigned short pl = f2bf(heff - bf2f(ph));
                unsigned* hbw = (cur ? hb0 : hb1);
                coh_store(hbw + brow_e * DD + ce, ((unsigned)ph << 16) | pl);
            }
        }

        if (t < TT - 1) {
            // ---- grid barrier: each wave drains its own coherent stores, then tree atomics ----
            asm volatile("s_waitcnt vmcnt(0)" ::: "memory");
            __syncthreads();
            if (tid == 0) {
                const unsigned grp = (unsigned)(wg >> 4);
                unsigned old = __hip_atomic_fetch_add(&bar[grp * 32], 1u,
                                                      __ATOMIC_RELAXED, __HIP_MEMORY_SCOPE_AGENT);
                if ((old & 15u) == 15u)
                    __hip_atomic_fetch_add(&bar[512], 1u, __ATOMIC_RELAXED, __HIP_MEMORY_SCOPE_AGENT);
                const unsigned target = (unsigned)(t + 1) * 16u;
                while (__hip_atomic_load(&bar[512], __ATOMIC_RELAXED, __HIP_MEMORY_SCOPE_AGENT) < target)
                    __builtin_amdgcn_s_sleep(1);
            }
            __syncthreads();
            cur ^= 1;
        }
    }
}

extern "C" void kernel_launch(void* const* d_in, const int* in_sizes, int n_in,
                              void* d_out, int out_size, void* d_ws, size_t ws_size,
                              hipStream_t stream) {
    const float* x = (const float*)d_in[0];
    const float* Wi = (const float*)d_in[1];
    const float* bi = (const float*)d_in[2];
    const float* Wh = (const float*)d_in[3];
    const float* bhn = (const float*)d_in[4];
    const unsigned char* resets = (const unsigned char*)d_in[5];
    float* out = (float*)d_out;
    unsigned char* ws = (unsigned char*)d_ws;

    if (ws_size < WS_NEED) return;  // would corrupt memory otherwise

    hipLaunchKernelGGL(prep_kernel, dim3(257), dim3(256), 0, stream, resets, ws);

    void* args[] = {(void*)&x, (void*)&Wi, (void*)&bi, (void*)&Wh,
                    (void*)&bhn, (void*)&resets, (void*)&out, (void*)&ws};
    hipError_t err = hipLaunchCooperativeKernel((const void*)gru_kernel, dim3(256), dim3(512),
                                                args, 0, stream);
    if (err != hipSuccess) {
        // fallback: plain launch — 256 WGs of 512 thr (1 per CU) co-reside on an idle MI355X
        hipLaunchKernelGGL(gru_kernel, dim3(256), dim3(512), 0, stream,
                           x, Wi, bi, Wh, bhn, resets, out, ws);
    }
}

// Round 3
// 2947.374 us; speedup vs baseline: 6.5381x; 1.8548x over previous
//
#include <hip/hip_runtime.h>

// GRU scan, T=512 B=64 D=1024. Persistent cooperative kernel:
// 256 WGs (4 M-groups x 64 col-groups), 512 thr (8 waves, K split 128/wave).
// Weights as persistent register MFMA B-fragments.
// x pre-split into bf16 hi/lo planes stashed in d_out (overwritten by results).
// h exchanged as bf16 hi/lo planes via sc1; flag-broadcast grid barrier.

typedef __attribute__((ext_vector_type(8))) short short8;
typedef __attribute__((ext_vector_type(4))) float f32x4;
typedef __attribute__((ext_vector_type(4))) unsigned int u32x4;

#define DEV static __device__ __forceinline__

constexpr int TT = 512, BB = 64, DD = 1024, TD = 3072;

constexpr size_t WS_BAR = 256;                 // barrier area base (bytes); prep zeroes words [0,2048)
constexpr size_t WS_H = 8192;                  // h planes: hb0_hi, hb0_lo, hb1_hi, hb1_lo (128 KB each)
constexpr size_t HPLANE = (size_t)BB * DD * 2; // bf16 plane bytes
constexpr size_t WS_NEED = WS_H + 4 * HPLANE;

DEV unsigned short f2bf(float f) {   // RNE float->bf16
    unsigned u = __builtin_bit_cast(unsigned, f);
    u += 0x7FFFu + ((u >> 16) & 1u);
    return (unsigned short)(u >> 16);
}
DEV float bf2f(unsigned short s) { return __builtin_bit_cast(float, ((unsigned)s) << 16); }

DEV void ld16_sc1(u32x4& r, const unsigned* p) {   // coherent 16B load (valid after vmcnt)
    asm volatile("global_load_dwordx4 %0, %1, off sc1" : "=v"(r) : "v"(p));
}
DEV void ld16(u32x4& r, const unsigned* p) {       // plain cached 16B load (valid after vmcnt)
    asm volatile("global_load_dwordx4 %0, %1, off" : "=v"(r) : "v"(p));
}
DEV void ld8u(unsigned& r, const unsigned char* p) {
    asm volatile("global_load_ubyte %0, %1, off" : "=v"(r) : "v"(p));
}
DEV void st16_sc1(unsigned short* p, unsigned v) {
    asm volatile("global_store_short %0, %1, off sc1" :: "v"(p), "v"(v) : "memory");
}
DEV void coh_store_u32(unsigned* p, unsigned v) {
    asm volatile("global_store_dword %0, %1, off sc1" :: "v"(p), "v"(v) : "memory");
}
DEV void vm0() {
    asm volatile("s_waitcnt vmcnt(0)" ::: "memory");
    __builtin_amdgcn_sched_barrier(0);   // rule #18
}

// ---------------- prepass A: split x into bf16 hi/lo planes inside d_out ----------------
// plane t (65536 f32 slots = 262144 B): words [0,32768) = x_hi bf16[64][1024], [32768,65536) = x_lo
__global__ void pack_x_kernel(const float* __restrict__ x, unsigned* __restrict__ outw) {
    const size_t gid = (size_t)blockIdx.x * 256 + threadIdx.x;
    const size_t e0 = gid * 8;
    const unsigned t = (unsigned)(e0 >> 16);
    const unsigned p = (unsigned)(e0 & 65535u);
    f32x4 a = *(const f32x4*)(x + e0);
    f32x4 b = *(const f32x4*)(x + e0 + 4);
    u32x4 wh, wl;
#pragma unroll
    for (int j = 0; j < 2; ++j) {
        unsigned short h0 = f2bf(a[2 * j]), h1 = f2bf(a[2 * j + 1]);
        wh[j] = (unsigned)h0 | ((unsigned)h1 << 16);
        wl[j] = (unsigned)f2bf(a[2 * j] - bf2f(h0)) | ((unsigned)f2bf(a[2 * j + 1] - bf2f(h1)) << 16);
        unsigned short g0 = f2bf(b[2 * j]), g1 = f2bf(b[2 * j + 1]);
        wh[2 + j] = (unsigned)g0 | ((unsigned)g1 << 16);
        wl[2 + j] = (unsigned)f2bf(b[2 * j] - bf2f(g0)) | ((unsigned)f2bf(b[2 * j + 1] - bf2f(g1)) << 16);
    }
    unsigned* base = outw + (size_t)t * 65536u;
    *(u32x4*)(base + (p >> 1)) = wh;
    *(u32x4*)(base + 32768u + (p >> 1)) = wl;
}

// ---------------- prepass B: zero h-buf0 + barrier area, detect resets element stride ----------------
__global__ void prep_kernel(const unsigned char* __restrict__ resets, unsigned char* __restrict__ ws) {
    const int bid = blockIdx.x, tid = threadIdx.x;
    if (bid < 256) {
        ((unsigned*)(ws + WS_H))[bid * 256 + tid] = 0u;   // zero hb0_hi + hb0_lo (256 KB)
    } else {
        unsigned* w32 = (unsigned*)ws;
        for (int i = tid; i < 2048; i += 256) w32[i] = 0u;
        __shared__ int ca, cb, cc;
        if (tid == 0) { ca = 0; cb = 0; cc = 0; }
        __syncthreads();
        int la = 0, lb = 0, lc = 0;
        for (int o = tid * 16; o < tid * 16 + 16; ++o) {
            unsigned char v = resets[o];
            if (v) {
                if ((o & 3) == 0) la = 1; else lb = 1;
                if ((o & 7) == 4) lc = 1;
            }
        }
        if (la) atomicOr(&ca, 1);
        if (lb) atomicOr(&cb, 1);
        if (lc) atomicOr(&cc, 1);
        __syncthreads();
        if (tid == 0) {
            unsigned stride, boff = 0;
            if (ca && cb)       { stride = 1; }
            else if (!ca && cb) { stride = 4; boff = 3; }
            else if (ca && cc)  { stride = 4; }
            else if (ca)        { stride = 8; }
            else                { stride = 4; }
            w32[0] = stride; w32[1] = boff;
        }
    }
}

// ---------------- barrier helpers (bar = u32* at ws+256) ----------------
// leaf[g] = bar[g*32] (g<16); root = bar[512]; flag[g] = bar[544+g*32]
DEV void arrive_epoch(unsigned* bar, int grp, unsigned ep) {
    unsigned old = __hip_atomic_fetch_add(&bar[grp * 32], 1u, __ATOMIC_RELAXED, __HIP_MEMORY_SCOPE_AGENT);
    if (old == ep * 16u - 1u) {
        unsigned oldr = __hip_atomic_fetch_add(&bar[512], 1u, __ATOMIC_RELAXED, __HIP_MEMORY_SCOPE_AGENT);
        if (oldr == ep * 16u - 1u) {
#pragma unroll
            for (int g = 0; g < 16; ++g) coh_store_u32(&bar[544 + g * 32], ep);
            asm volatile("s_waitcnt vmcnt(0)" ::: "memory");
        }
    }
}
DEV void wait_epoch(unsigned* bar, int grp, unsigned ep) {
    while (__hip_atomic_load(&bar[544 + grp * 32], __ATOMIC_RELAXED, __HIP_MEMORY_SCOPE_AGENT) < ep) {}
}

// ---------------- main persistent kernel ----------------
__launch_bounds__(512, 1)
__global__ void gru_kernel(const float* __restrict__ Wi, const float* __restrict__ bi,
                           const float* __restrict__ Wh, const float* __restrict__ bhn,
                           const unsigned char* __restrict__ resets,
                           float* __restrict__ out, unsigned char* __restrict__ ws) {
    const int tid = threadIdx.x;
    const int wg = blockIdx.x;
    const int lane = tid & 63;
    const int kw = tid >> 6;          // wave id 0..7: K-slice [kw*128, +128)
    const int mgrp = wg >> 6;         // rows [mgrp*16, +16)
    const int c0 = (wg & 63) * 16;    // h-column group
    const int grp = wg >> 4;          // barrier group

    unsigned* bar = (unsigned*)(ws + WS_BAR);
    const unsigned rstride = ((const unsigned*)ws)[0];
    const unsigned rboff   = ((const unsigned*)ws)[1];

    unsigned short* h_hi[2] = {(unsigned short*)(ws + WS_H),
                               (unsigned short*)(ws + WS_H + 2 * HPLANE)};
    unsigned short* h_lo[2] = {(unsigned short*)(ws + WS_H + HPLANE),
                               (unsigned short*)(ws + WS_H + 3 * HPLANE)};
    unsigned* outw = (unsigned*)out;

    const int lrow = lane & 15;
    const int lk = (lane >> 4) * 8;

    // ---- persistent B fragments (Wi_hi, Wh_hi, Wh_lo): 144 VGPR ----
    short8 bih[3][4], bhh[3][4], bhl[3][4];
#pragma unroll
    for (int nt = 0; nt < 3; ++nt) {
        const int col = nt * DD + c0 + lrow;
#pragma unroll
        for (int kt = 0; kt < 4; ++kt) {
            const int kb = kw * 128 + kt * 32 + lk;
            short8 a, c, d;
#pragma unroll
            for (int j = 0; j < 8; ++j) {
                float wi = Wi[(size_t)(kb + j) * TD + col];
                a[j] = (short)f2bf(wi);
                float wh = Wh[(size_t)(kb + j) * TD + col];
                unsigned short h2 = f2bf(wh);
                c[j] = (short)h2;
                d[j] = (short)f2bf(wh - bf2f(h2));
            }
            bih[nt][kt] = a; bhh[nt][kt] = c; bhl[nt][kt] = d;
        }
    }

    // ---- epilogue constants ----
    const int eb = (tid & 255) >> 4, ej = tid & 15;
    const int brow = mgrp * 16 + eb;
    const int ce = c0 + ej;
    const float bi_r = bi[ce], bi_z = bi[DD + ce], bi_n = bi[2 * DD + ce];
    const float bh_n = bhn[ce];
    float h_local = 0.f;

    const int arow = mgrp * 16 + lrow;
    const unsigned hidx = (unsigned)(arow * DD + kw * 128 + lk);   // halfword index, even
    const size_t r64 = (size_t)64 * rstride;
    const size_t roffb = (size_t)brow * rstride + rboff;

    __shared__ float pgi[8][3][16][18];
    __shared__ float pgh[8][3][16][18];
    const int prow = (lane >> 4) * 4;

    // ================= prologue: gi for step 0 =================
    {
        const unsigned* xpl = outw;  // plane 0
        u32x4 xf[8];
#pragma unroll
        for (int kt = 0; kt < 4; ++kt) {
            ld16(xf[2 * kt],     xpl + ((hidx + kt * 32) >> 1));
            ld16(xf[2 * kt + 1], xpl + 32768u + ((hidx + kt * 32) >> 1));
        }
        vm0();
        f32x4 ai[3] = {f32x4{0}, f32x4{0}, f32x4{0}};
#pragma unroll
        for (int kt = 0; kt < 4; ++kt) {
            short8 xh = __builtin_bit_cast(short8, xf[2 * kt]);
            short8 xl = __builtin_bit_cast(short8, xf[2 * kt + 1]);
#pragma unroll
            for (int nt = 0; nt < 3; ++nt)
                ai[nt] = __builtin_amdgcn_mfma_f32_16x16x32_bf16(xh, bih[nt][kt], ai[nt], 0, 0, 0);
#pragma unroll
            for (int nt = 0; nt < 3; ++nt)
                ai[nt] = __builtin_amdgcn_mfma_f32_16x16x32_bf16(xl, bih[nt][kt], ai[nt], 0, 0, 0);
        }
#pragma unroll
        for (int s = 0; s < 3; ++s)
#pragma unroll
            for (int i = 0; i < 4; ++i)
                pgi[kw][s][prow + i][lrow] = ai[s][i];
        __syncthreads();
        if (tid == 0) arrive_epoch(bar, grp, 1u);
    }

    int cur = 0;
    // ================= main loop: t = 0 .. TT-2 =================
    for (int t = 0; t < TT - 1; ++t) {
        if (tid == 0) wait_epoch(bar, grp, (unsigned)(t + 1));
        __syncthreads();

        // (2) coherent h loads (only vm ops outstanding)
        const unsigned* hhp = (const unsigned*)h_hi[cur];
        const unsigned* hlp = (const unsigned*)h_lo[cur];
        u32x4 hf[8];
#pragma unroll
        for (int kt = 0; kt < 4; ++kt) {
            ld16_sc1(hf[2 * kt],     hhp + ((hidx + kt * 32) >> 1));
            ld16_sc1(hf[2 * kt + 1], hlp + ((hidx + kt * 32) >> 1));
        }

        // (3) reduce gi partials (LDS only; overlaps h latency)
        float g0 = 0.f, g1 = 0.f, g2 = 0.f;
        if (tid < 256) {
#pragma unroll
            for (int k = 0; k < 8; ++k) {
                g0 += pgi[k][0][eb][ej];
                g1 += pgi[k][1][eb][ej];
                g2 += pgi[k][2][eb][ej];
            }
        }

        vm0();   // h ready

        // (4) issue x[t+1] frag loads + resets byte (consumed after next vm0)
        const unsigned* xpl = outw + (size_t)(t + 1) * 65536u;
        u32x4 xf[8];
#pragma unroll
        for (int kt = 0; kt < 4; ++kt) {
            ld16(xf[2 * kt],     xpl + ((hidx + kt * 32) >> 1));
            ld16(xf[2 * kt + 1], xpl + 32768u + ((hidx + kt * 32) >> 1));
        }
        unsigned rsv;
        ld8u(rsv, resets + roffb + (size_t)(t + 1) * r64);

        // (5) h-MFMAs: gh = h_hi@Wh_hi + h_lo@Wh_hi + h_hi@Wh_lo
        f32x4 ag[3] = {f32x4{0}, f32x4{0}, f32x4{0}};
#pragma unroll
        for (int kt = 0; kt < 4; ++kt) {
            short8 hh = __builtin_bit_cast(short8, hf[2 * kt]);
            short8 hl = __builtin_bit_cast(short8, hf[2 * kt + 1]);
#pragma unroll
            for (int nt = 0; nt < 3; ++nt)
                ag[nt] = __builtin_amdgcn_mfma_f32_16x16x32_bf16(hh, bhh[nt][kt], ag[nt], 0, 0, 0);
#pragma unroll
            for (int nt = 0; nt < 3; ++nt)
                ag[nt] = __builtin_amdgcn_mfma_f32_16x16x32_bf16(hl, bhh[nt][kt], ag[nt], 0, 0, 0);
#pragma unroll
            for (int nt = 0; nt < 3; ++nt)
                ag[nt] = __builtin_amdgcn_mfma_f32_16x16x32_bf16(hh, bhl[nt][kt], ag[nt], 0, 0, 0);
        }

        // (6) publish gh partials
#pragma unroll
        for (int s = 0; s < 3; ++s)
#pragma unroll
            for (int i = 0; i < 4; ++i)
                pgh[kw][s][prow + i][lrow] = ag[s][i];
        __syncthreads();

        vm0();   // x frags + resets ready

        // (8) gi MFMAs for step t+1
        f32x4 ai[3] = {f32x4{0}, f32x4{0}, f32x4{0}};
#pragma unroll
        for (int kt = 0; kt < 4; ++kt) {
            short8 xh = __builtin_bit_cast(short8, xf[2 * kt]);
            short8 xl = __builtin_bit_cast(short8, xf[2 * kt + 1]);
#pragma unroll
            for (int nt = 0; nt < 3; ++nt)
                ai[nt] = __builtin_amdgcn_mfma_f32_16x16x32_bf16(xh, bih[nt][kt], ai[nt], 0, 0, 0);
#pragma unroll
            for (int nt = 0; nt < 3; ++nt)
                ai[nt] = __builtin_amdgcn_mfma_f32_16x16x32_bf16(xl, bih[nt][kt], ai[nt], 0, 0, 0);
        }
#pragma unroll
        for (int s = 0; s < 3; ++s)    // gi reads of this iter finished before pgh sync
#pragma unroll
            for (int i = 0; i < 4; ++i)
                pgi[kw][s][prow + i][lrow] = ai[s][i];

        // (9) epilogue
        if (tid < 256) {
            float h0 = 0.f, h1 = 0.f, h2 = 0.f;
#pragma unroll
            for (int k = 0; k < 8; ++k) {
                h0 += pgh[k][0][eb][ej];
                h1 += pgh[k][1][eb][ej];
                h2 += pgh[k][2][eb][ej];
            }
            float r = 1.f / (1.f + __expf(-(g0 + bi_r + h0)));
            float z = 1.f / (1.f + __expf(-(g1 + bi_z + h1)));
            float pre = g2 + bi_n + r * (h2 + bh_n);
            float e2 = __expf(2.f * pre);
            float n = 1.f - 2.f / (e2 + 1.f);
            float hnew = (1.f - z) * n + z * h_local;

            out[(size_t)t * 65536u + brow * DD + ce] = hnew;

            float heff = (rsv != 0u) ? 0.f : hnew;
            h_local = heff;
            unsigned short ph = f2bf(heff);
            unsigned short pl = f2bf(heff - bf2f(ph));
            st16_sc1(h_hi[cur ^ 1] + brow * DD + ce, (unsigned)ph);
            st16_sc1(h_lo[cur ^ 1] + brow * DD + ce, (unsigned)pl);
        }

        // (10) drain own stores, then arrive
        asm volatile("s_waitcnt vmcnt(0)" ::: "memory");
        __syncthreads();
        if (tid == 0) arrive_epoch(bar, grp, (unsigned)(t + 2));
        cur ^= 1;
    }

    // ================= peeled last step t = TT-1 =================
    {
        const int t = TT - 1;
        if (tid == 0) wait_epoch(bar, grp, (unsigned)TT);
        __syncthreads();

        const unsigned* hhp = (const unsigned*)h_hi[cur];
        const unsigned* hlp = (const unsigned*)h_lo[cur];
        u32x4 hf[8];
#pragma unroll
        for (int kt = 0; kt < 4; ++kt) {
            ld16_sc1(hf[2 * kt],     hhp + ((hidx + kt * 32) >> 1));
            ld16_sc1(hf[2 * kt + 1], hlp + ((hidx + kt * 32) >> 1));
        }
        float g0 = 0.f, g1 = 0.f, g2 = 0.f;
        if (tid < 256) {
#pragma unroll
            for (int k = 0; k < 8; ++k) {
                g0 += pgi[k][0][eb][ej];
                g1 += pgi[k][1][eb][ej];
                g2 += pgi[k][2][eb][ej];
            }
        }
        vm0();
        f32x4 ag[3] = {f32x4{0}, f32x4{0}, f32x4{0}};
#pragma unroll
        for (int kt = 0; kt < 4; ++kt) {
            short8 hh = __builtin_bit_cast(short8, hf[2 * kt]);
            short8 hl = __builtin_bit_cast(short8, hf[2 * kt + 1]);
#pragma unroll
            for (int nt = 0; nt < 3; ++nt)
                ag[nt] = __builtin_amdgcn_mfma_f32_16x16x32_bf16(hh, bhh[nt][kt], ag[nt], 0, 0, 0);
#pragma unroll
            for (int nt = 0; nt < 3; ++nt)
                ag[nt] = __builtin_amdgcn_mfma_f32_16x16x32_bf16(hl, bhh[nt][kt], ag[nt], 0, 0, 0);
#pragma unroll
            for (int nt = 0; nt < 3; ++nt)
                ag[nt] = __builtin_amdgcn_mfma_f32_16x16x32_bf16(hh, bhl[nt][kt], ag[nt], 0, 0, 0);
        }
#pragma unroll
        for (int s = 0; s < 3; ++s)
#pragma unroll
            for (int i = 0; i < 4; ++i)
                pgh[kw][s][prow + i][lrow] = ag[s][i];
        __syncthreads();

        if (tid < 256) {
            float h0 = 0.f, h1 = 0.f, h2 = 0.f;
#pragma unroll
            for (int k = 0; k < 8; ++k) {
                h0 += pgh[k][0][eb][ej];
                h1 += pgh[k][1][eb][ej];
                h2 += pgh[k][2][eb][ej];
            }
            float r = 1.f / (1.f + __expf(-(g0 + bi_r + h0)));
            float z = 1.f / (1.f + __expf(-(g1 + bi_z + h1)));
            float pre = g2 + bi_n + r * (h2 + bh_n);
            float e2 = __expf(2.f * pre);
            float n = 1.f - 2.f / (e2 + 1.f);
            float hnew = (1.f - z) * n + z * h_local;
            out[(size_t)t * 65536u + brow * DD + ce] = hnew;
        }
    }
}

extern "C" void kernel_launch(void* const* d_in, const int* in_sizes, int n_in,
                              void* d_out, int out_size, void* d_ws, size_t ws_size,
                              hipStream_t stream) {
    const float* x = (const float*)d_in[0];
    const float* Wi = (const float*)d_in[1];
    const float* bi = (const float*)d_in[2];
    const float* Wh = (const float*)d_in[3];
    const float* bhn = (const float*)d_in[4];
    const unsigned char* resets = (const unsigned char*)d_in[5];
    float* out = (float*)d_out;
    unsigned char* ws = (unsigned char*)d_ws;

    if (ws_size < WS_NEED) return;

    hipLaunchKernelGGL(pack_x_kernel, dim3(16384), dim3(256), 0, stream, x, (unsigned*)out);
    hipLaunchKernelGGL(prep_kernel, dim3(257), dim3(256), 0, stream, resets, ws);

    void* args[] = {(void*)&Wi, (void*)&bi, (void*)&Wh, (void*)&bhn,
                    (void*)&resets, (void*)&out, (void*)&ws};
    hipError_t err = hipLaunchCooperativeKernel((const void*)gru_kernel, dim3(256), dim3(512),
                                                args, 0, stream);
    if (err != hipSuccess) {
        hipLaunchKernelGGL(gru_kernel, dim3(256), dim3(512), 0, stream,
                           Wi, bi, Wh, bhn, resets, out, ws);
    }
}